// Round 1
// 92.286 us; speedup vs baseline: 1.0106x; 1.0106x over previous
//
#include <hip/hip_runtime.h>
#include <math.h>

// Fidelity of 4-qubit embedding circuits: out = |<psi(f2)|psi(f1)>|^2,
// psi(f) = [diag(P(f)) * (1/4) * WHT16]^3 |0>, P folds all RZ + ZZ phases of
// one layer. One thread per sample; the 16-amp complex state lives in VGPRs.
//
// vs previous version (93.3us measured, kernel ~11us of it, rest = harness
// poison fills):
//  - phases computed in REVOLUTIONS; v_fract + raw v_sin/v_cos (no rint/fma
//    range reduction per state)
//  - 16-entry phi table built by Walsh-butterfly CSE (~30 adds, was ~112)
//  - tables unscaled; whole (1/4)^6 normalization = one exact *2^-24 at end
//  - first WHT stage of each circuit reads the table directly (kills the
//    64 v_mov state-init copies; cs/sn stay live for the diagonals)

#define PI_F     3.14159265358979323846f
#define INV2PI_F 0.15915494309189535f

// Unscaled 16-pt Walsh-Hadamard, in place. Stages commute (one per bit).
__device__ __forceinline__ void wht16(float a[16]) {
#pragma unroll
    for (int m = 1; m < 16; m <<= 1) {
#pragma unroll
        for (int s = 0; s < 16; ++s) {
            if (!(s & m)) {
                float u = a[s], v = a[s | m];
                a[s] = u + v; a[s | m] = u - v;
            }
        }
    }
}

// Same, but the first stage streams from src (saves copying src into a).
__device__ __forceinline__ void wht16_from(const float src[16], float a[16]) {
#pragma unroll
    for (int s = 0; s < 16; ++s) {
        if (!(s & 1)) {
            float u = src[s], v = src[s | 1];
            a[s] = u + v; a[s | 1] = u - v;
        }
    }
#pragma unroll
    for (int m = 2; m < 16; m <<= 1) {
#pragma unroll
        for (int s = 0; s < 16; ++s) {
            if (!(s & m)) {
                float u = a[s], v = a[s | m];
                a[s] = u + v; a[s | m] = u - v;
            }
        }
    }
}

__device__ __forceinline__ void diag_mul(float re[16], float im[16],
                                         const float cs[16], const float sn[16]) {
#pragma unroll
    for (int s = 0; s < 16; ++s) {
        float r = fmaf(-im[s], sn[s], re[s] * cs[s]);
        float i = fmaf( im[s], cs[s], re[s] * sn[s]);
        re[s] = r; im[s] = i;
    }
}

// Phase table, UNSCALED: cs[s]=cos(phi_s), sn[s]=sin(phi_s).
// Wire w maps to bit (3-w). With sigma_j = +-1 per bit:
//   phi = -(f0 s0 + f1 s1 + f2 s2 + f3 s3)
//         + p01 s0s1 + p12 s1s2 + p23 s2s3 + p30 s3s0,  p_ab = (pi-f_a)(pi-f_b)
// Walsh CSE: with e=s0s1, g=s2s3, h=s0s2 (as 0/1 for +/-):
//   linear = -s0 * (A_e + h*B_g),  A0/1 = f0+-f1, B0/1 = f2+-f3
//   quad   =  e  * (P_i + h*R_i),  i = e^g, P0/1 = p01+-p23, R0/1 = p12+-p30
// Everything premultiplied by 1/2pi so phases are in revolutions for v_sin.
__device__ __forceinline__ void phase_table(const float f[4], float cs[16], float sn[16]) {
    float g0 = PI_F - f[0], g1 = PI_F - f[1], g2 = PI_F - f[2], g3 = PI_F - f[3];
    float f0r = f[0] * INV2PI_F, f1r = f[1] * INV2PI_F;
    float f2r = f[2] * INV2PI_F, f3r = f[3] * INV2PI_F;
    float g1r = g1 * INV2PI_F, g3r = g3 * INV2PI_F;
    float p01 = g0 * g1r, p12 = g1r * g2, p23 = g2 * g3r, p30 = g3r * g0;

    float A0 = f0r + f1r, A1 = f0r - f1r, B0 = f2r + f3r, B1 = f2r - f3r;
    float P0 = p01 + p23, P1 = p01 - p23, R0 = p12 + p30, R1 = p12 - p30;
    float Lt[8] = {A0 + B0, A0 - B0, A0 + B1, A0 - B1,
                   A1 + B0, A1 - B0, A1 + B1, A1 - B1};   // [e][g][h]
    float Qt[4] = {P0 + R0, P0 - R0, P1 + R1, P1 - R1};   // [e^g][h]
#pragma unroll
    for (int s = 0; s < 16; ++s) {
        const int sa = (s >> 3) & 1, sb = (s >> 2) & 1;
        const int sc = (s >> 1) & 1, sd = s & 1;
        const int e = sa ^ sb, g = sc ^ sd, h = sa ^ sc;  // 0 => product +1
        const float Lv = Lt[e * 4 + g * 2 + h];
        const float Qv = Qt[(e ^ g) * 2 + h];
        // phi (revolutions) = -sigma0*Lv + sign(e)*Qv; one v_add w/ modifiers
        float t = (sa ? -Lv : Lv) + (e ? -Qv : Qv);
        t = __builtin_amdgcn_fractf(t);          // v_sin wants [0,1) revs
        sn[s] = __builtin_amdgcn_sinf(t);
        cs[s] = __builtin_amdgcn_cosf(t);
    }
}

// psi_unscaled = [diag(P) * WHT16]^3 |0>  (= 64 * psi). Layer 1 is the table.
__device__ __forceinline__ void run_circuit(const float cs[16], const float sn[16],
                                            float re[16], float im[16]) {
    wht16_from(cs, re);
    wht16_from(sn, im);
    diag_mul(re, im, cs, sn);
    wht16(re);
    wht16(im);
    diag_mul(re, im, cs, sn);
}

// MLP 4->8->8->4 on two inputs simultaneously (weight loads stay scalar).
__device__ __forceinline__ void mlp_dual(
    const float xa[4], const float xb[4],
    const float* __restrict__ W1, const float* __restrict__ b1,
    const float* __restrict__ W2, const float* __restrict__ b2,
    const float* __restrict__ W3, const float* __restrict__ b3,
    float fa[4], float fb[4]) {
    float h1a[8], h1b[8];
#pragma unroll
    for (int k = 0; k < 8; ++k) {
        float aa = b1[k], ab = aa;
#pragma unroll
        for (int j = 0; j < 4; ++j) {
            float w = W1[j * 8 + k];
            aa = fmaf(xa[j], w, aa);
            ab = fmaf(xb[j], w, ab);
        }
        h1a[k] = fmaxf(aa, 0.f);
        h1b[k] = fmaxf(ab, 0.f);
    }
    float h2a[8], h2b[8];
#pragma unroll
    for (int k = 0; k < 8; ++k) {
        float aa = b2[k], ab = aa;
#pragma unroll
        for (int j = 0; j < 8; ++j) {
            float w = W2[j * 8 + k];
            aa = fmaf(h1a[j], w, aa);
            ab = fmaf(h1b[j], w, ab);
        }
        h2a[k] = fmaxf(aa, 0.f);
        h2b[k] = fmaxf(ab, 0.f);
    }
#pragma unroll
    for (int k = 0; k < 4; ++k) {
        float aa = b3[k], ab = aa;
#pragma unroll
        for (int j = 0; j < 8; ++j) {
            float w = W3[j * 4 + k];
            aa = fmaf(h2a[j], w, aa);
            ab = fmaf(h2b[j], w, ab);
        }
        fa[k] = aa;
        fb[k] = ab;
    }
}

__global__ __launch_bounds__(256) void fidelity_kernel(
    const float* __restrict__ x1, const float* __restrict__ x2,
    const float* __restrict__ W1, const float* __restrict__ b1,
    const float* __restrict__ W2, const float* __restrict__ b2,
    const float* __restrict__ W3, const float* __restrict__ b3,
    float* __restrict__ out, int n) {
    int tid = blockIdx.x * 256 + threadIdx.x;
    if (tid >= n) return;

    float4 a4 = ((const float4*)x1)[tid];
    float4 b4 = ((const float4*)x2)[tid];
    float xa[4] = {a4.x, a4.y, a4.z, a4.w};
    float xb[4] = {b4.x, b4.y, b4.z, b4.w};

    float fa[4], fb[4];
    mlp_dual(xa, xb, W1, b1, W2, b2, W3, b3, fa, fb);

    float cs[16], sn[16];
    float re1[16], im1[16];
    phase_table(fa, cs, sn);
    run_circuit(cs, sn, re1, im1);

    float re2[16], im2[16];
    phase_table(fb, cs, sn);
    run_circuit(cs, sn, re2, im2);

    // <psi2|psi1>_unscaled = 4096 * <psi2|psi1>
    float dr = 0.f, di = 0.f;
#pragma unroll
    for (int s = 0; s < 16; ++s) {
        dr = fmaf(re2[s], re1[s], dr);
        dr = fmaf(im2[s], im1[s], dr);
        di = fmaf(re2[s], im1[s], di);
        di = fmaf(-im2[s], re1[s], di);
    }
    // |dot|^2 * 2^-24 restores the (1/4)^3 per circuit, exactly representable
    out[tid] = fmaf(dr, dr, di * di) * 5.9604644775390625e-8f;
}

extern "C" void kernel_launch(void* const* d_in, const int* in_sizes, int n_in,
                              void* d_out, int out_size, void* d_ws, size_t ws_size,
                              hipStream_t stream) {
    const float* x1 = (const float*)d_in[0];
    const float* x2 = (const float*)d_in[1];
    const float* W1 = (const float*)d_in[2];
    const float* b1 = (const float*)d_in[3];
    const float* W2 = (const float*)d_in[4];
    const float* b2 = (const float*)d_in[5];
    const float* W3 = (const float*)d_in[6];
    const float* b3 = (const float*)d_in[7];
    float* out = (float*)d_out;

    int n = out_size;  // B samples
    int block = 256;
    int grid = (n + block - 1) / block;
    fidelity_kernel<<<grid, block, 0, stream>>>(x1, x2, W1, b1, W2, b2, W3, b3, out, n);
}